// Round 9
// baseline (259.583 us; speedup 1.0000x reference)
//
#include <hip/hip_runtime.h>
#include <math.h>

#define NN 102400
#define FD 128
#define KC 16
#define BG 64
#define NPG 1600
#define NE 3276800
#define HB 640           // edge-range blocks (hist phase + scatter)
#define EH (NE / HB)     // 5120 edges per block
#define EPT (EH / 256)   // 20 edges per thread
#define BINS 256         // (graph, row-quarter): bin = src/400
#define RPB 400          // rows per bin
#define NPB 160          // nodes per k_s2 block (640 blocks, 10 per graph)

__device__ __forceinline__ void glob_addf(float* p, float v) {
  unsafeAtomicAdd(p, v);
}
__device__ __forceinline__ unsigned f2bf(float f) {
  unsigned u = __float_as_uint(f);
  u += 0x7FFFu + ((u >> 16) & 1u);
  return (u >> 16) & 0xFFFFu;
}
__device__ __forceinline__ float bf2f(unsigned h) {
  return __uint_as_float(h << 16);
}

// ---- k_s2: fused {edge histogram} + {softmax^2(x@W+b)} + {S^T X partials} ----
// 640 blocks x 256 threads; block b = (graph b/10, sub b%10) owns 160 nodes and
// edge range [b*EH,(b+1)*EH). Phase-2 re-reads the block's 82KB x-tile L2-hot.
// CC moved to k_post (from s, L3-resident) to keep partials small.
__global__ __launch_bounds__(256, 4) void k_s2(const float* __restrict__ x,
    const float* __restrict__ W, const float* __restrict__ bb,
    const int* __restrict__ esrc, float* __restrict__ s,
    unsigned short* __restrict__ blkhist, float* __restrict__ outx_part) {
  __shared__ float st[NPB * KC];        // 10.24 KB
  __shared__ unsigned h[BINS];          // 1 KB
  const int t = threadIdx.x, b = blockIdx.x;
  const int g = b / 10, sub = b % 10;
  const int n0 = g * NPG + sub * NPB;
  // ---- phase 0: histogram of this block's edge range ----
  h[t] = 0u;
  __syncthreads();
  const int e0 = b * EH;
  for (int i = t; i < EH; i += 256) {
    unsigned bin = (unsigned)esrc[e0 + i] / (unsigned)RPB;
    atomicAdd(&h[bin], 1u);             // ds_add, no-return
  }
  __syncthreads();
  blkhist[t * HB + b] = (unsigned short)h[t];
  // ---- phase 1: softmax^2 for nodes n0..n0+159 (threads 0..159) ----
  if (t < NPB) {
    float acc[KC];
#pragma unroll
    for (int k = 0; k < KC; ++k) acc[k] = bb[k];
    const float4* xr = (const float4*)(x + (size_t)(n0 + t) * FD);
#pragma unroll 4
    for (int c = 0; c < FD / 4; ++c) {
      float4 v = xr[c];
      const float* wr = W + c * 4 * KC;   // wave-uniform -> scalar loads
#pragma unroll
      for (int k = 0; k < KC; ++k)
        acc[k] += v.x * wr[k] + v.y * wr[KC + k] + v.z * wr[2 * KC + k] + v.w * wr[3 * KC + k];
    }
#pragma unroll
    for (int r = 0; r < 2; ++r) {
      float m = acc[0];
#pragma unroll
      for (int k = 1; k < KC; ++k) m = fmaxf(m, acc[k]);
      float sum = 0.f;
#pragma unroll
      for (int k = 0; k < KC; ++k) { acc[k] = expf(acc[k] - m); sum += acc[k]; }
      float inv = 1.f / sum;
#pragma unroll
      for (int k = 0; k < KC; ++k) acc[k] *= inv;
    }
#pragma unroll
    for (int k = 0; k < KC; ++k) st[t * KC + k] = acc[k];
    float4* so = (float4*)(s + (size_t)(n0 + t) * KC);
    so[0] = make_float4(acc[0], acc[1], acc[2], acc[3]);
    so[1] = make_float4(acc[4], acc[5], acc[6], acc[7]);
    so[2] = make_float4(acc[8], acc[9], acc[10], acc[11]);
    so[3] = make_float4(acc[12], acc[13], acc[14], acc[15]);
  }
  __syncthreads();
  // ---- phase 2: out_x = S^T X partial over the block's 160 rows ----
  const int j = t & 127, h2 = t >> 7;
  float accX[8] = {0.f, 0.f, 0.f, 0.f, 0.f, 0.f, 0.f, 0.f};
  for (int i = 0; i < NPB; ++i) {
    const float xv = x[(size_t)(n0 + i) * FD + j];   // L2-hot (phase-1 tile)
    const float* si = st + i * KC;
#pragma unroll
    for (int kk = 0; kk < 8; ++kk) accX[kk] = fmaf(si[h2 * 8 + kk], xv, accX[kk]);
  }
#pragma unroll
  for (int kk = 0; kk < 8; ++kk)
    outx_part[(size_t)b * 2048 + (h2 * 8 + kk) * 128 + j] = accX[kk];
}

// ------- scan A (256 bins x HB entries, u16) + zero adj/scal/done -------
__global__ __launch_bounds__(640) void k_scan_a(unsigned short* __restrict__ blkhist,
    unsigned* __restrict__ gtot, unsigned* __restrict__ azero) {
  __shared__ unsigned wsum[10];
  const int t = threadIdx.x, bin = blockIdx.x;
  const int lane = t & 63;
  const unsigned zi = (unsigned)bin * 640u + (unsigned)t;
  if (zi < 16400u) azero[zi] = 0u;      // adj_raw(16384) + scal(8) + done(8)
  unsigned v = blkhist[bin * HB + t];
  unsigned inc = v;
#pragma unroll
  for (int o = 1; o < 64; o <<= 1) {
    unsigned nb = __shfl_up(inc, o, 64);
    if (lane >= o) inc += nb;
  }
  if (lane == 63) wsum[t >> 6] = inc;
  __syncthreads();
  if (t == 0) {
    unsigned run = 0;
#pragma unroll
    for (int i = 0; i < 10; ++i) { unsigned c = wsum[i]; wsum[i] = run; run += c; }
    gtot[bin] = run;
  }
  __syncthreads();
  blkhist[bin * HB + t] = (unsigned short)(inc - v + wsum[t >> 6]);
}

// ------ scatter v2: reg snapshot -> LDS bin-sorted stage -> burst out ------
// In-block gbase scan from gtot (k_scan_b deleted); u8 bmap instead of u32 gofs
// (LDS 38KB -> up to 4 blocks/CU). Burst flush completes 64B lines in-window.
__global__ __launch_bounds__(256, 4) void k_scatter2(const float* __restrict__ ew,
    const int* __restrict__ esrc, const int* __restrict__ edst,
    const unsigned short* __restrict__ blkhist, const unsigned* __restrict__ gtot,
    unsigned short* __restrict__ skey, unsigned* __restrict__ pay) {
  __shared__ unsigned cur[BINS];        // counts -> cursors
  __shared__ unsigned gadj[BINS];       // gstart[bin] - boff[bin]
  __shared__ unsigned wsum[4];
  __shared__ unsigned pays[EH];         // 20.5 KB
  __shared__ unsigned short keys[EH];   // 10.25 KB
  __shared__ unsigned char bmap[EH];    // 5.1 KB
  const int t = threadIdx.x, b = blockIdx.x;
  // in-block exclusive scan of gtot -> gbase[t]
  const unsigned gv = gtot[t];
  unsigned ginc = gv;
#pragma unroll
  for (int o = 1; o < 64; o <<= 1) {
    unsigned nb = __shfl_up(ginc, o, 64);
    if ((t & 63) >= o) ginc += nb;
  }
  if ((t & 63) == 63) wsum[t >> 6] = ginc;
  __syncthreads();
  if (t == 0) {
    unsigned run = 0;
#pragma unroll
    for (int i = 0; i < 4; ++i) { unsigned c = wsum[i]; wsum[i] = run; run += c; }
  }
  __syncthreads();
  const unsigned gstart = (ginc - gv + wsum[t >> 6]) + blkhist[t * HB + b];
  cur[t] = 0u;
  __syncthreads();
  // pass 1: snapshot edges into registers + block histogram
  unsigned rpay[EPT], rmeta[EPT];       // rmeta = bin<<16 | row-in-bin
  const int e0 = b * EH;
#pragma unroll
  for (int i = 0; i < EPT; ++i) {
    const int e = e0 + t + i * 256;
    int s0 = esrc[e], d0 = edst[e];
    float w = ew[e];
    unsigned bin = (unsigned)s0 / (unsigned)RPB;
    unsigned g = bin >> 2;
    rmeta[i] = (bin << 16) | ((unsigned)s0 - bin * RPB);
    rpay[i] = (((unsigned)d0 - g * NPG) << 16) | f2bf(w);
    atomicAdd(&cur[bin], 1u);           // ds_add, no-return
  }
  __syncthreads();
  // exclusive scan of cur[256] -> block-local offsets; set cursors + gadj
  {
    unsigned v = cur[t];
    unsigned inc = v;
#pragma unroll
    for (int o = 1; o < 64; o <<= 1) {
      unsigned nb = __shfl_up(inc, o, 64);
      if ((t & 63) >= o) inc += nb;
    }
    if ((t & 63) == 63) wsum[t >> 6] = inc;
    __syncthreads();
    if (t == 0) {
      unsigned run = 0;
#pragma unroll
      for (int i = 0; i < 4; ++i) { unsigned c = wsum[i]; wsum[i] = run; run += c; }
    }
    __syncthreads();
    const unsigned boff = inc - v + wsum[t >> 6];
    cur[t] = boff;                      // running cursor starts at boff
    gadj[t] = gstart - boff;            // gaddr = gadj[bin] + pos
  }
  __syncthreads();
  // pass 2: rank + scatter into LDS staging (bin-sorted order)
#pragma unroll
  for (int i = 0; i < EPT; ++i) {
    const unsigned bin = rmeta[i] >> 16;
    const unsigned pos = atomicAdd(&cur[bin], 1u);   // ds_add_rtn
    pays[pos] = rpay[i];
    keys[pos] = (unsigned short)(rmeta[i] & 0xFFFFu);
    bmap[pos] = (unsigned char)bin;
  }
  __syncthreads();
  // pass 3: burst flush; consecutive p -> consecutive gaddr within each bin run
  for (int p = t; p < EH; p += 256) {
    const unsigned bin = bmap[p];
    const unsigned ga = gadj[bin] + p;
    pay[ga] = pays[p];
    skey[ga] = keys[p];
  }
}

// ---- k_msc3: s slab in LDS; M bin accumulator in LDS as FIXED-POINT u32 ----
// ds_add_u32 fire-and-forget (FP LDS atomicAdd = CAS loop, R5 lesson). 8-deep
// chains halve serial LDS steps; in-block gbase scan from gtot.
__global__ __launch_bounds__(1024, 1) void k_msc3(const float* __restrict__ s,
    const unsigned short* __restrict__ skey, const unsigned* __restrict__ pay,
    const unsigned* __restrict__ gtot, float* __restrict__ adj_raw,
    float* __restrict__ den) {
  __shared__ float SL[NPG * 17];       // 108.8 KB: whole-graph s, stride-17 pad
  __shared__ unsigned Ml[RPB * 17];    // 27.2 KB: bin's M accumulator (x 2^24)
  __shared__ float P[1024];            // 4 KB: adj partial reduce
  __shared__ float scr[16];
  __shared__ unsigned gbl[257];
  const int t = threadIdx.x;
  // swizzle: all 4 bins of a graph (and 8 graphs) share an XCD
  const int bin = (blockIdx.x & 7) * 32 + (blockIdx.x >> 3);
  const int g = bin >> 2;
  const int q = bin & 3;
  // wave 0: exclusive scan of gtot -> gbl[257]
  if (t < 64) {
    unsigned v0 = gtot[t * 4], v1 = gtot[t * 4 + 1];
    unsigned v2 = gtot[t * 4 + 2], v3 = gtot[t * 4 + 3];
    unsigned sum = v0 + v1 + v2 + v3;
    unsigned inc = sum;
#pragma unroll
    for (int o = 1; o < 64; o <<= 1) {
      unsigned nb = __shfl_up(inc, o, 64);
      if (t >= o) inc += nb;
    }
    unsigned ex = inc - sum;
    gbl[t * 4] = ex;
    gbl[t * 4 + 1] = ex + v0;
    gbl[t * 4 + 2] = ex + v0 + v1;
    gbl[t * 4 + 3] = ex + v0 + v1 + v2;
    if (t == 63) gbl[256] = inc;
  }
  // stage s slab, converting [1600][16] -> padded [1600][17]
  const float4* sg4 = (const float4*)(s + (size_t)g * NPG * KC);
  for (int u4 = t; u4 < NPG * KC / 4; u4 += 1024) {
    float4 v = sg4[u4];
    const int u = u4 * 4;
    float* d = &SL[(u >> 4) * 17 + (u & 15)];
    d[0] = v.x; d[1] = v.y; d[2] = v.z; d[3] = v.w;
  }
  for (int i = t; i < RPB * 17; i += 1024) Ml[i] = 0u;
  __syncthreads();
  const unsigned gb = gbl[bin], ge = gbl[bin + 1];
  const int l = t & 15;
  const int gid = t >> 4;              // 0..63 edge-group id
  const float FXS = 16777216.f;        // 2^24 fixed-point scale
  float dacc = 0.f;
  unsigned e = gb + gid;
  for (; e + 448 < ge; e += 512) {     // 8 independent chains per lane
    unsigned pk0 = pay[e],       pk1 = pay[e + 64];
    unsigned pk2 = pay[e + 128], pk3 = pay[e + 192];
    unsigned pk4 = pay[e + 256], pk5 = pay[e + 320];
    unsigned pk6 = pay[e + 384], pk7 = pay[e + 448];
    unsigned sk0 = skey[e],       sk1 = skey[e + 64];
    unsigned sk2 = skey[e + 128], sk3 = skey[e + 192];
    unsigned sk4 = skey[e + 256], sk5 = skey[e + 320];
    unsigned sk6 = skey[e + 384], sk7 = skey[e + 448];
    float sv0 = SL[(pk0 >> 16) * 17 + l];
    float sv1 = SL[(pk1 >> 16) * 17 + l];
    float sv2 = SL[(pk2 >> 16) * 17 + l];
    float sv3 = SL[(pk3 >> 16) * 17 + l];
    float sv4 = SL[(pk4 >> 16) * 17 + l];
    float sv5 = SL[(pk5 >> 16) * 17 + l];
    float sv6 = SL[(pk6 >> 16) * 17 + l];
    float sv7 = SL[(pk7 >> 16) * 17 + l];
    float t0 = bf2f(pk0 & 0xFFFFu) * sv0;
    float t1 = bf2f(pk1 & 0xFFFFu) * sv1;
    float t2 = bf2f(pk2 & 0xFFFFu) * sv2;
    float t3 = bf2f(pk3 & 0xFFFFu) * sv3;
    float t4 = bf2f(pk4 & 0xFFFFu) * sv4;
    float t5 = bf2f(pk5 & 0xFFFFu) * sv5;
    float t6 = bf2f(pk6 & 0xFFFFu) * sv6;
    float t7 = bf2f(pk7 & 0xFFFFu) * sv7;
    dacc = fmaf(t0, sv0, dacc);
    dacc = fmaf(t1, sv1, dacc);
    dacc = fmaf(t2, sv2, dacc);
    dacc = fmaf(t3, sv3, dacc);
    dacc = fmaf(t4, sv4, dacc);
    dacc = fmaf(t5, sv5, dacc);
    dacc = fmaf(t6, sv6, dacc);
    dacc = fmaf(t7, sv7, dacc);
    atomicAdd(&Ml[sk0 * 17 + l], __float2uint_rn(t0 * FXS));  // ds_add_u32
    atomicAdd(&Ml[sk1 * 17 + l], __float2uint_rn(t1 * FXS));
    atomicAdd(&Ml[sk2 * 17 + l], __float2uint_rn(t2 * FXS));
    atomicAdd(&Ml[sk3 * 17 + l], __float2uint_rn(t3 * FXS));
    atomicAdd(&Ml[sk4 * 17 + l], __float2uint_rn(t4 * FXS));
    atomicAdd(&Ml[sk5 * 17 + l], __float2uint_rn(t5 * FXS));
    atomicAdd(&Ml[sk6 * 17 + l], __float2uint_rn(t6 * FXS));
    atomicAdd(&Ml[sk7 * 17 + l], __float2uint_rn(t7 * FXS));
  }
  for (; e < ge; e += 64) {
    unsigned pk0 = pay[e];
    unsigned sk0 = skey[e];
    float sv0 = SL[(pk0 >> 16) * 17 + l];
    float t0 = bf2f(pk0 & 0xFFFFu) * sv0;
    dacc = fmaf(t0, sv0, dacc);
    atomicAdd(&Ml[sk0 * 17 + l], __float2uint_rn(t0 * FXS));
  }
  __syncthreads();
  // adj contraction: cell (ck,cl) over the bin's 400 rows; 4 threads per cell
  const int ck = (t >> 4) & 15, cl = t & 15, sub = t >> 8;
  float pacc = 0.f;
  const float* SLq = SL + q * RPB * 17;
#pragma unroll 4
  for (int ii = 0; ii < RPB / 4; ++ii) {
    const int r = sub + 4 * ii;
    pacc = fmaf(SLq[r * 17 + ck], (float)Ml[r * 17 + cl], pacc);
  }
  P[t] = pacc;
#pragma unroll
  for (int o = 32; o > 0; o >>= 1) dacc += __shfl_down(dacc, o, 64);
  if ((t & 63) == 0) scr[t >> 6] = dacc;
  __syncthreads();
  if (t < 256) glob_addf(adj_raw + g * 256 + t,
                         (P[t] + P[t + 256] + P[t + 512] + P[t + 768])
                             * 5.9604644775390625e-8f);   // x 2^-24
  if (t == 0) {
    float sum = 0.f;
#pragma unroll
    for (int i = 0; i < 16; ++i) sum += scr[i];
    glob_addf(den, sum);
  }
}

// ---- k_post: normalize adj, trace, CC+ortho (from s), SELU (outx partials) ----
__device__ __forceinline__ float bred(float v, float* scr) {
#pragma unroll
  for (int o = 32; o > 0; o >>= 1) v += __shfl_down(v, o, 64);
  __syncthreads();
  if ((threadIdx.x & 63) == 0) scr[threadIdx.x >> 6] = v;
  __syncthreads();
  return scr[0] + scr[1] + scr[2] + scr[3];
}

__global__ __launch_bounds__(256) void k_post(const float* __restrict__ adj_raw,
    const float* __restrict__ s, const float* __restrict__ outx_part,
    float* __restrict__ out, float* __restrict__ scal, unsigned* __restrict__ done) {
  const int b = blockIdx.x, t = threadIdx.x;
  const int k = t >> 4, l = t & 15;
  __shared__ float m[16 * 17];
  __shared__ float dk[16];
  __shared__ float scr[4];
  __shared__ float st2[100 * KC];       // 6.4 KB CC staging
  const float raw = adj_raw[b * 256 + t];
  const float masked = (k == l) ? 0.f : raw;
  m[k * 17 + l] = masked;
  __syncthreads();
  if (t < 16) {
    float rs = 0.f;
#pragma unroll
    for (int ll = 0; ll < 16; ++ll) rs += m[t * 17 + ll];
    dk[t] = sqrtf(rs) + 1e-12f;
  }
  __syncthreads();
  out[131072 + b * 256 + t] = masked / (dk[k] * dk[l]);
  float tr = bred((k == l) ? raw : 0.f, scr);
  if (t == 0) glob_addf(scal + 1, tr);
  // CC = S^T S for this graph, 16 chunks of 100 rows (s is L2/L3-resident)
  const float* sG = s + (size_t)b * NPG * KC;
  float c = 0.f;
  for (int ch = 0; ch < 16; ++ch) {
    __syncthreads();
    for (int u = t; u < 100 * KC; u += 256) st2[u] = sG[ch * 100 * KC + u];
    __syncthreads();
#pragma unroll 4
    for (int i = 0; i < 100; ++i) c = fmaf(st2[i * KC + k], st2[i * KC + l], c);
  }
  float n2 = bred(c * c, scr);
  float diff = c / sqrtf(n2) - ((k == l) ? 0.25f : 0.f);
  float d2 = bred(diff * diff, scr);
  if (t == 0) glob_addf(scal + 2, sqrtf(d2));
  for (int idx = b * 256 + t; idx < 131072; idx += 16384) {
    const int gg = idx >> 11, v = idx & 2047;
    float xv = 0.f;
#pragma unroll
    for (int u = 0; u < 10; ++u) xv += outx_part[(size_t)(gg * 10 + u) * 2048 + v];
    out[idx] = xv > 0.f ? 1.0507009873554805f * xv
                        : 1.0507009873554805f * 1.6732632423543772f * expm1f(xv);
  }
  __syncthreads();
  if (t == 0) {
    __threadfence();
    unsigned v = __hip_atomic_fetch_add(done, 1u, __ATOMIC_ACQ_REL,
                                        __HIP_MEMORY_SCOPE_AGENT);
    if (v == 63u) {   // last block: all contributions visible
      float den   = __hip_atomic_load(scal + 0, __ATOMIC_RELAXED, __HIP_MEMORY_SCOPE_AGENT);
      float num   = __hip_atomic_load(scal + 1, __ATOMIC_RELAXED, __HIP_MEMORY_SCOPE_AGENT);
      float ortho = __hip_atomic_load(scal + 2, __ATOMIC_RELAXED, __HIP_MEMORY_SCOPE_AGENT);
      out[147456] = -num / den;
      out[147457] = ortho * (1.f / 64.f);
    }
  }
}

// -------------------- launch --------------------
extern "C" void kernel_launch(void* const* d_in, const int* in_sizes, int n_in,
                              void* d_out, int out_size, void* d_ws, size_t ws_size,
                              hipStream_t stream) {
  const float* x  = (const float*)d_in[0];
  const float* W  = (const float*)d_in[1];
  const float* bb = (const float*)d_in[2];
  const float* ew = (const float*)d_in[3];
  const int* esrc = (const int*)d_in[4];
  const int* edst = (const int*)d_in[5];
  float* out = (float*)d_out;
  float* ws = (float*)d_ws;

  float* s_buf    = ws;                                   // 1,638,400 f
  float* adj_raw  = s_buf + (size_t)NN * KC;              // 16,384 f  <- zeroed by scan_a
  float* scal     = adj_raw + 16384;                      // 8 f: [0]=den [1]=num [2]=ortho
  unsigned* done  = (unsigned*)(scal + 8);                // 8 u       <- end of zero region
  float* outx_part= (float*)(done + 8);                   // 640*2048 f (per-block partials)
  unsigned* gtot  = (unsigned*)(outx_part + (size_t)HB * 2048);  // 256 u
  unsigned short* blkhist = (unsigned short*)(gtot + BINS);      // 256*640 u16
  unsigned short* skey = blkhist + (size_t)BINS * HB;     // NE u16
  unsigned* pay = (unsigned*)(skey + NE);                 // NE u32 (dst-in-graph<<16 | bf16 w)
  // total ~= 30.4 MB (< 33.4 MB proven available)

  k_s2<<<HB, 256, 0, stream>>>(x, W, bb, esrc, s_buf, blkhist, outx_part);
  k_scan_a<<<BINS, 640, 0, stream>>>(blkhist, gtot, (unsigned*)adj_raw);
  k_scatter2<<<HB, 256, 0, stream>>>(ew, esrc, edst, blkhist, gtot, skey, pay);
  k_msc3<<<BINS, 1024, 0, stream>>>(s_buf, skey, pay, gtot, adj_raw, scal);
  k_post<<<64, 256, 0, stream>>>(adj_raw, s_buf, outx_part, out, scal, done);
}

// Round 10
// 214.803 us; speedup vs baseline: 1.2085x; 1.2085x over previous
//
#include <hip/hip_runtime.h>
#include <math.h>

#define NN 102400
#define FD 128
#define KC 16
#define BG 64
#define NPG 1600
#define NE 3276800
#define HB 640           // edge-range blocks (hist phase + scatter)
#define EH (NE / HB)     // 5120 edges per block
#define EPT (EH / 256)   // 20 edges per thread
#define BINS 256         // (graph, row-quarter): bin = src/400
#define RPB 400          // rows per bin
#define NPB 160          // nodes per k_s2 block (640 blocks, 10 per graph)

__device__ __forceinline__ void glob_addf(float* p, float v) {
  unsafeAtomicAdd(p, v);
}
__device__ __forceinline__ unsigned f2bf(float f) {
  unsigned u = __float_as_uint(f);
  u += 0x7FFFu + ((u >> 16) & 1u);
  return (u >> 16) & 0xFFFFu;
}
__device__ __forceinline__ float bf2f(unsigned h) {
  return __uint_as_float(h << 16);
}

// ---- k_s2: fused {edge histogram} + {softmax^2(x@W+b)} + {CC, S^T X partials} ----
// 640 blocks x 256 threads; block b = (graph b/10, sub b%10) owns 160 nodes and
// edge range [b*EH,(b+1)*EH). Phase-2 re-reads the block's 82KB x-tile L2-hot.
// CC back as per-block partials (R9 post-mortem: CC in 64-block k_post = 2.5%
// occupancy, +55us; here it rides an already-running loop for ~free).
__global__ __launch_bounds__(256, 4) void k_s2(const float* __restrict__ x,
    const float* __restrict__ W, const float* __restrict__ bb,
    const int* __restrict__ esrc, float* __restrict__ s,
    unsigned short* __restrict__ blkhist, float* __restrict__ cc_part,
    float* __restrict__ outx_part) {
  __shared__ float st[NPB * KC];        // 10.24 KB
  __shared__ unsigned h[BINS];          // 1 KB
  const int t = threadIdx.x, b = blockIdx.x;
  const int g = b / 10, sub = b % 10;
  const int n0 = g * NPG + sub * NPB;
  // ---- phase 0: histogram of this block's edge range ----
  h[t] = 0u;
  __syncthreads();
  const int e0 = b * EH;
  for (int i = t; i < EH; i += 256) {
    unsigned bin = (unsigned)esrc[e0 + i] / (unsigned)RPB;
    atomicAdd(&h[bin], 1u);             // ds_add, no-return
  }
  __syncthreads();
  blkhist[t * HB + b] = (unsigned short)h[t];
  // ---- phase 1: softmax^2 for nodes n0..n0+159 (threads 0..159) ----
  if (t < NPB) {
    float acc[KC];
#pragma unroll
    for (int k = 0; k < KC; ++k) acc[k] = bb[k];
    const float4* xr = (const float4*)(x + (size_t)(n0 + t) * FD);
#pragma unroll 4
    for (int c = 0; c < FD / 4; ++c) {
      float4 v = xr[c];
      const float* wr = W + c * 4 * KC;   // wave-uniform -> scalar loads
#pragma unroll
      for (int k = 0; k < KC; ++k)
        acc[k] += v.x * wr[k] + v.y * wr[KC + k] + v.z * wr[2 * KC + k] + v.w * wr[3 * KC + k];
    }
#pragma unroll
    for (int r = 0; r < 2; ++r) {
      float m = acc[0];
#pragma unroll
      for (int k = 1; k < KC; ++k) m = fmaxf(m, acc[k]);
      float sum = 0.f;
#pragma unroll
      for (int k = 0; k < KC; ++k) { acc[k] = expf(acc[k] - m); sum += acc[k]; }
      float inv = 1.f / sum;
#pragma unroll
      for (int k = 0; k < KC; ++k) acc[k] *= inv;
    }
#pragma unroll
    for (int k = 0; k < KC; ++k) st[t * KC + k] = acc[k];
    float4* so = (float4*)(s + (size_t)(n0 + t) * KC);
    so[0] = make_float4(acc[0], acc[1], acc[2], acc[3]);
    so[1] = make_float4(acc[4], acc[5], acc[6], acc[7]);
    so[2] = make_float4(acc[8], acc[9], acc[10], acc[11]);
    so[3] = make_float4(acc[12], acc[13], acc[14], acc[15]);
  }
  __syncthreads();
  // ---- phase 2: out_x = S^T X and CC = S^T S partials over the block's 160 rows ----
  const int j = t & 127, h2 = t >> 7;
  const int kc = t >> 4, lc = t & 15;
  float accX[8] = {0.f, 0.f, 0.f, 0.f, 0.f, 0.f, 0.f, 0.f};
  float accC = 0.f;
  for (int i = 0; i < NPB; ++i) {
    const float xv = x[(size_t)(n0 + i) * FD + j];   // L2-hot (phase-1 tile)
    const float* si = st + i * KC;
#pragma unroll
    for (int kk = 0; kk < 8; ++kk) accX[kk] = fmaf(si[h2 * 8 + kk], xv, accX[kk]);
    accC = fmaf(si[kc], si[lc], accC);
  }
#pragma unroll
  for (int kk = 0; kk < 8; ++kk)
    outx_part[(size_t)b * 2048 + (h2 * 8 + kk) * 128 + j] = accX[kk];
  cc_part[b * 256 + t] = accC;
}

// ------- scan A (256 bins x HB entries, u16) + zero adj/scal/done -------
__global__ __launch_bounds__(640) void k_scan_a(unsigned short* __restrict__ blkhist,
    unsigned* __restrict__ gtot, unsigned* __restrict__ azero) {
  __shared__ unsigned wsum[10];
  const int t = threadIdx.x, bin = blockIdx.x;
  const int lane = t & 63;
  const unsigned zi = (unsigned)bin * 640u + (unsigned)t;
  if (zi < 16400u) azero[zi] = 0u;      // adj_raw(16384) + scal(8) + done(8)
  unsigned v = blkhist[bin * HB + t];
  unsigned inc = v;
#pragma unroll
  for (int o = 1; o < 64; o <<= 1) {
    unsigned nb = __shfl_up(inc, o, 64);
    if (lane >= o) inc += nb;
  }
  if (lane == 63) wsum[t >> 6] = inc;
  __syncthreads();
  if (t == 0) {
    unsigned run = 0;
#pragma unroll
    for (int i = 0; i < 10; ++i) { unsigned c = wsum[i]; wsum[i] = run; run += c; }
    gtot[bin] = run;
  }
  __syncthreads();
  blkhist[bin * HB + t] = (unsigned short)(inc - v + wsum[t >> 6]);
}

// ------ scatter v2: reg snapshot -> LDS bin-sorted stage -> burst out ------
// In-block gbase scan from gtot; u8 bmap staging. Burst flush completes 64B
// lines within the window (R7: WRITE 142MB -> ~30MB).
__global__ __launch_bounds__(256, 4) void k_scatter2(const float* __restrict__ ew,
    const int* __restrict__ esrc, const int* __restrict__ edst,
    const unsigned short* __restrict__ blkhist, const unsigned* __restrict__ gtot,
    unsigned short* __restrict__ skey, unsigned* __restrict__ pay) {
  __shared__ unsigned cur[BINS];        // counts -> cursors
  __shared__ unsigned gadj[BINS];       // gstart[bin] - boff[bin]
  __shared__ unsigned wsum[4];
  __shared__ unsigned pays[EH];         // 20.5 KB
  __shared__ unsigned short keys[EH];   // 10.25 KB
  __shared__ unsigned char bmap[EH];    // 5.1 KB
  const int t = threadIdx.x, b = blockIdx.x;
  // in-block exclusive scan of gtot -> gbase[t]
  const unsigned gv = gtot[t];
  unsigned ginc = gv;
#pragma unroll
  for (int o = 1; o < 64; o <<= 1) {
    unsigned nb = __shfl_up(ginc, o, 64);
    if ((t & 63) >= o) ginc += nb;
  }
  if ((t & 63) == 63) wsum[t >> 6] = ginc;
  __syncthreads();
  if (t == 0) {
    unsigned run = 0;
#pragma unroll
    for (int i = 0; i < 4; ++i) { unsigned c = wsum[i]; wsum[i] = run; run += c; }
  }
  __syncthreads();
  const unsigned gstart = (ginc - gv + wsum[t >> 6]) + blkhist[t * HB + b];
  cur[t] = 0u;
  __syncthreads();
  // pass 1: snapshot edges into registers + block histogram
  unsigned rpay[EPT], rmeta[EPT];       // rmeta = bin<<16 | row-in-bin
  const int e0 = b * EH;
#pragma unroll
  for (int i = 0; i < EPT; ++i) {
    const int e = e0 + t + i * 256;
    int s0 = esrc[e], d0 = edst[e];
    float w = ew[e];
    unsigned bin = (unsigned)s0 / (unsigned)RPB;
    unsigned g = bin >> 2;
    rmeta[i] = (bin << 16) | ((unsigned)s0 - bin * RPB);
    rpay[i] = (((unsigned)d0 - g * NPG) << 16) | f2bf(w);
    atomicAdd(&cur[bin], 1u);           // ds_add, no-return
  }
  __syncthreads();
  // exclusive scan of cur[256] -> block-local offsets; set cursors + gadj
  {
    unsigned v = cur[t];
    unsigned inc = v;
#pragma unroll
    for (int o = 1; o < 64; o <<= 1) {
      unsigned nb = __shfl_up(inc, o, 64);
      if ((t & 63) >= o) inc += nb;
    }
    if ((t & 63) == 63) wsum[t >> 6] = inc;
    __syncthreads();
    if (t == 0) {
      unsigned run = 0;
#pragma unroll
      for (int i = 0; i < 4; ++i) { unsigned c = wsum[i]; wsum[i] = run; run += c; }
    }
    __syncthreads();
    const unsigned boff = inc - v + wsum[t >> 6];
    cur[t] = boff;                      // running cursor starts at boff
    gadj[t] = gstart - boff;            // gaddr = gadj[bin] + pos
  }
  __syncthreads();
  // pass 2: rank + scatter into LDS staging (bin-sorted order)
#pragma unroll
  for (int i = 0; i < EPT; ++i) {
    const unsigned bin = rmeta[i] >> 16;
    const unsigned pos = atomicAdd(&cur[bin], 1u);   // ds_add_rtn
    pays[pos] = rpay[i];
    keys[pos] = (unsigned short)(rmeta[i] & 0xFFFFu);
    bmap[pos] = (unsigned char)bin;
  }
  __syncthreads();
  // pass 3: burst flush; consecutive p -> consecutive gaddr within each bin run
  for (int p = t; p < EH; p += 256) {
    const unsigned bin = bmap[p];
    const unsigned ga = gadj[bin] + p;
    pay[ga] = pays[p];
    skey[ga] = keys[p];
  }
}

// ---- k_msc3: s slab in LDS; M bin accumulator in LDS as FIXED-POINT u32 ----
// ds_add_u32 fire-and-forget (FP LDS atomicAdd = CAS loop, R5 lesson). 8-deep
// chains halve serial LDS steps; in-block gbase scan from gtot.
__global__ __launch_bounds__(1024, 1) void k_msc3(const float* __restrict__ s,
    const unsigned short* __restrict__ skey, const unsigned* __restrict__ pay,
    const unsigned* __restrict__ gtot, float* __restrict__ adj_raw,
    float* __restrict__ den) {
  __shared__ float SL[NPG * 17];       // 108.8 KB: whole-graph s, stride-17 pad
  __shared__ unsigned Ml[RPB * 17];    // 27.2 KB: bin's M accumulator (x 2^24)
  __shared__ float P[1024];            // 4 KB: adj partial reduce
  __shared__ float scr[16];
  __shared__ unsigned gbl[257];
  const int t = threadIdx.x;
  // swizzle: all 4 bins of a graph (and 8 graphs) share an XCD
  const int bin = (blockIdx.x & 7) * 32 + (blockIdx.x >> 3);
  const int g = bin >> 2;
  const int q = bin & 3;
  // wave 0: exclusive scan of gtot -> gbl[257]
  if (t < 64) {
    unsigned v0 = gtot[t * 4], v1 = gtot[t * 4 + 1];
    unsigned v2 = gtot[t * 4 + 2], v3 = gtot[t * 4 + 3];
    unsigned sum = v0 + v1 + v2 + v3;
    unsigned inc = sum;
#pragma unroll
    for (int o = 1; o < 64; o <<= 1) {
      unsigned nb = __shfl_up(inc, o, 64);
      if (t >= o) inc += nb;
    }
    unsigned ex = inc - sum;
    gbl[t * 4] = ex;
    gbl[t * 4 + 1] = ex + v0;
    gbl[t * 4 + 2] = ex + v0 + v1;
    gbl[t * 4 + 3] = ex + v0 + v1 + v2;
    if (t == 63) gbl[256] = inc;
  }
  // stage s slab, converting [1600][16] -> padded [1600][17]
  const float4* sg4 = (const float4*)(s + (size_t)g * NPG * KC);
  for (int u4 = t; u4 < NPG * KC / 4; u4 += 1024) {
    float4 v = sg4[u4];
    const int u = u4 * 4;
    float* d = &SL[(u >> 4) * 17 + (u & 15)];
    d[0] = v.x; d[1] = v.y; d[2] = v.z; d[3] = v.w;
  }
  for (int i = t; i < RPB * 17; i += 1024) Ml[i] = 0u;
  __syncthreads();
  const unsigned gb = gbl[bin], ge = gbl[bin + 1];
  const int l = t & 15;
  const int gid = t >> 4;              // 0..63 edge-group id
  const float FXS = 16777216.f;        // 2^24 fixed-point scale
  float dacc = 0.f;
  unsigned e = gb + gid;
  for (; e + 448 < ge; e += 512) {     // 8 independent chains per lane
    unsigned pk0 = pay[e],       pk1 = pay[e + 64];
    unsigned pk2 = pay[e + 128], pk3 = pay[e + 192];
    unsigned pk4 = pay[e + 256], pk5 = pay[e + 320];
    unsigned pk6 = pay[e + 384], pk7 = pay[e + 448];
    unsigned sk0 = skey[e],       sk1 = skey[e + 64];
    unsigned sk2 = skey[e + 128], sk3 = skey[e + 192];
    unsigned sk4 = skey[e + 256], sk5 = skey[e + 320];
    unsigned sk6 = skey[e + 384], sk7 = skey[e + 448];
    float sv0 = SL[(pk0 >> 16) * 17 + l];
    float sv1 = SL[(pk1 >> 16) * 17 + l];
    float sv2 = SL[(pk2 >> 16) * 17 + l];
    float sv3 = SL[(pk3 >> 16) * 17 + l];
    float sv4 = SL[(pk4 >> 16) * 17 + l];
    float sv5 = SL[(pk5 >> 16) * 17 + l];
    float sv6 = SL[(pk6 >> 16) * 17 + l];
    float sv7 = SL[(pk7 >> 16) * 17 + l];
    float t0 = bf2f(pk0 & 0xFFFFu) * sv0;
    float t1 = bf2f(pk1 & 0xFFFFu) * sv1;
    float t2 = bf2f(pk2 & 0xFFFFu) * sv2;
    float t3 = bf2f(pk3 & 0xFFFFu) * sv3;
    float t4 = bf2f(pk4 & 0xFFFFu) * sv4;
    float t5 = bf2f(pk5 & 0xFFFFu) * sv5;
    float t6 = bf2f(pk6 & 0xFFFFu) * sv6;
    float t7 = bf2f(pk7 & 0xFFFFu) * sv7;
    dacc = fmaf(t0, sv0, dacc);
    dacc = fmaf(t1, sv1, dacc);
    dacc = fmaf(t2, sv2, dacc);
    dacc = fmaf(t3, sv3, dacc);
    dacc = fmaf(t4, sv4, dacc);
    dacc = fmaf(t5, sv5, dacc);
    dacc = fmaf(t6, sv6, dacc);
    dacc = fmaf(t7, sv7, dacc);
    atomicAdd(&Ml[sk0 * 17 + l], __float2uint_rn(t0 * FXS));  // ds_add_u32
    atomicAdd(&Ml[sk1 * 17 + l], __float2uint_rn(t1 * FXS));
    atomicAdd(&Ml[sk2 * 17 + l], __float2uint_rn(t2 * FXS));
    atomicAdd(&Ml[sk3 * 17 + l], __float2uint_rn(t3 * FXS));
    atomicAdd(&Ml[sk4 * 17 + l], __float2uint_rn(t4 * FXS));
    atomicAdd(&Ml[sk5 * 17 + l], __float2uint_rn(t5 * FXS));
    atomicAdd(&Ml[sk6 * 17 + l], __float2uint_rn(t6 * FXS));
    atomicAdd(&Ml[sk7 * 17 + l], __float2uint_rn(t7 * FXS));
  }
  for (; e < ge; e += 64) {
    unsigned pk0 = pay[e];
    unsigned sk0 = skey[e];
    float sv0 = SL[(pk0 >> 16) * 17 + l];
    float t0 = bf2f(pk0 & 0xFFFFu) * sv0;
    dacc = fmaf(t0, sv0, dacc);
    atomicAdd(&Ml[sk0 * 17 + l], __float2uint_rn(t0 * FXS));
  }
  __syncthreads();
  // adj contraction: cell (ck,cl) over the bin's 400 rows; 4 threads per cell
  const int ck = (t >> 4) & 15, cl = t & 15, sub = t >> 8;
  float pacc = 0.f;
  const float* SLq = SL + q * RPB * 17;
#pragma unroll 4
  for (int ii = 0; ii < RPB / 4; ++ii) {
    const int r = sub + 4 * ii;
    pacc = fmaf(SLq[r * 17 + ck], (float)Ml[r * 17 + cl], pacc);
  }
  P[t] = pacc;
#pragma unroll
  for (int o = 32; o > 0; o >>= 1) dacc += __shfl_down(dacc, o, 64);
  if ((t & 63) == 0) scr[t >> 6] = dacc;
  __syncthreads();
  if (t < 256) glob_addf(adj_raw + g * 256 + t,
                         (P[t] + P[t + 256] + P[t + 512] + P[t + 768])
                             * 5.9604644775390625e-8f);   // x 2^-24
  if (t == 0) {
    float sum = 0.f;
#pragma unroll
    for (int i = 0; i < 16; ++i) sum += scr[i];
    glob_addf(den, sum);
  }
}

// ---- k_post: normalize adj, trace, ortho (CC partial sum), SELU (outx partials) ----
__device__ __forceinline__ float bred(float v, float* scr) {
#pragma unroll
  for (int o = 32; o > 0; o >>= 1) v += __shfl_down(v, o, 64);
  __syncthreads();
  if ((threadIdx.x & 63) == 0) scr[threadIdx.x >> 6] = v;
  __syncthreads();
  return scr[0] + scr[1] + scr[2] + scr[3];
}

__global__ __launch_bounds__(256) void k_post(const float* __restrict__ adj_raw,
    const float* __restrict__ cc_part, const float* __restrict__ outx_part,
    float* __restrict__ out, float* __restrict__ scal, unsigned* __restrict__ done) {
  const int b = blockIdx.x, t = threadIdx.x;
  const int k = t >> 4, l = t & 15;
  __shared__ float m[16 * 17];
  __shared__ float dk[16];
  __shared__ float scr[4];
  const float raw = adj_raw[b * 256 + t];
  const float masked = (k == l) ? 0.f : raw;
  m[k * 17 + l] = masked;
  __syncthreads();
  if (t < 16) {
    float rs = 0.f;
#pragma unroll
    for (int ll = 0; ll < 16; ++ll) rs += m[t * 17 + ll];
    dk[t] = sqrtf(rs) + 1e-12f;
  }
  __syncthreads();
  out[131072 + b * 256 + t] = masked / (dk[k] * dk[l]);
  float tr = bred((k == l) ? raw : 0.f, scr);
  if (t == 0) glob_addf(scal + 1, tr);
  float c = 0.f;
#pragma unroll
  for (int u = 0; u < 10; ++u) c += cc_part[(b * 10 + u) * 256 + t];
  float n2 = bred(c * c, scr);
  float diff = c / sqrtf(n2) - ((k == l) ? 0.25f : 0.f);
  float d2 = bred(diff * diff, scr);
  if (t == 0) glob_addf(scal + 2, sqrtf(d2));
  for (int idx = b * 256 + t; idx < 131072; idx += 16384) {
    const int gg = idx >> 11, v = idx & 2047;
    float xv = 0.f;
#pragma unroll
    for (int u = 0; u < 10; ++u) xv += outx_part[(size_t)(gg * 10 + u) * 2048 + v];
    out[idx] = xv > 0.f ? 1.0507009873554805f * xv
                        : 1.0507009873554805f * 1.6732632423543772f * expm1f(xv);
  }
  __syncthreads();
  if (t == 0) {
    __threadfence();
    unsigned v = __hip_atomic_fetch_add(done, 1u, __ATOMIC_ACQ_REL,
                                        __HIP_MEMORY_SCOPE_AGENT);
    if (v == 63u) {   // last block: all contributions visible
      float den   = __hip_atomic_load(scal + 0, __ATOMIC_RELAXED, __HIP_MEMORY_SCOPE_AGENT);
      float num   = __hip_atomic_load(scal + 1, __ATOMIC_RELAXED, __HIP_MEMORY_SCOPE_AGENT);
      float ortho = __hip_atomic_load(scal + 2, __ATOMIC_RELAXED, __HIP_MEMORY_SCOPE_AGENT);
      out[147456] = -num / den;
      out[147457] = ortho * (1.f / 64.f);
    }
  }
}

// -------------------- launch --------------------
extern "C" void kernel_launch(void* const* d_in, const int* in_sizes, int n_in,
                              void* d_out, int out_size, void* d_ws, size_t ws_size,
                              hipStream_t stream) {
  const float* x  = (const float*)d_in[0];
  const float* W  = (const float*)d_in[1];
  const float* bb = (const float*)d_in[2];
  const float* ew = (const float*)d_in[3];
  const int* esrc = (const int*)d_in[4];
  const int* edst = (const int*)d_in[5];
  float* out = (float*)d_out;
  float* ws = (float*)d_ws;

  float* s_buf    = ws;                                   // 1,638,400 f
  float* adj_raw  = s_buf + (size_t)NN * KC;              // 16,384 f  <- zeroed by scan_a
  float* scal     = adj_raw + 16384;                      // 8 f: [0]=den [1]=num [2]=ortho
  unsigned* done  = (unsigned*)(scal + 8);                // 8 u       <- end of zero region
  float* cc_part  = (float*)(done + 8);                   // 640*256 f  (per-block partials)
  float* outx_part= cc_part + (size_t)HB * 256;           // 640*2048 f (per-block partials)
  unsigned* gtot  = (unsigned*)(outx_part + (size_t)HB * 2048);  // 256 u
  unsigned short* blkhist = (unsigned short*)(gtot + BINS);      // 256*640 u16
  unsigned short* skey = blkhist + (size_t)BINS * HB;     // NE u16
  unsigned* pay = (unsigned*)(skey + NE);                 // NE u32 (dst-in-graph<<16 | bf16 w)
  // total ~= 31.1 MB (< 33.4 MB proven available)

  k_s2<<<HB, 256, 0, stream>>>(x, W, bb, esrc, s_buf, blkhist, cc_part, outx_part);
  k_scan_a<<<BINS, 640, 0, stream>>>(blkhist, gtot, (unsigned*)adj_raw);
  k_scatter2<<<HB, 256, 0, stream>>>(ew, esrc, edst, blkhist, gtot, skey, pay);
  k_msc3<<<BINS, 1024, 0, stream>>>(s_buf, skey, pay, gtot, adj_raw, scal);
  k_post<<<64, 256, 0, stream>>>(adj_raw, cc_part, outx_part, out, scal, done);
}

// Round 11
// 213.062 us; speedup vs baseline: 1.2183x; 1.0082x over previous
//
#include <hip/hip_runtime.h>
#include <math.h>

#define NN 102400
#define FD 128
#define KC 16
#define BG 64
#define NPG 1600
#define NE 3276800
#define HB 640           // scatter edge-range blocks
#define EH (NE / HB)     // 5120 edges per block
#define EPT (EH / 256)   // 20 edges per thread
#define BINS 256         // (graph, row-quarter): bin = src/400
#define RPB 400          // rows per bin
#define CAP 13824        // fixed bin capacity (mean 12800, sigma~113 -> +9 sigma)
#define NPB 200          // nodes per k_s2 block (512 blocks, 8 per graph)
#define SB 512           // k_s2 blocks

__device__ __forceinline__ void glob_addf(float* p, float v) {
  unsafeAtomicAdd(p, v);
}
__device__ __forceinline__ unsigned f2bf(float f) {
  unsigned u = __float_as_uint(f);
  u += 0x7FFFu + ((u >> 16) & 1u);
  return (u >> 16) & 0xFFFFu;
}
__device__ __forceinline__ float bf2f(unsigned h) {
  return __uint_as_float(h << 16);
}

// ---- k_s2: fused {softmax^2(x@W+b)} + {CC, S^T X partials} + zero/init ----
// 512 blocks x 256 threads; block b = (graph b/8, sub b%8) owns 200 nodes.
// Histogram phase DELETED (fixed-capacity bins + atomic reservation in scatter).
// Phase-2 re-reads the block's 102KB x-tile L2-hot (proven R8: FETCH ~= x once).
__global__ __launch_bounds__(256, 4) void k_s2(const float* __restrict__ x,
    const float* __restrict__ W, const float* __restrict__ bb,
    float* __restrict__ s, float* __restrict__ cc_part,
    float* __restrict__ outx_part, unsigned* __restrict__ azero,
    unsigned* __restrict__ gcur) {
  __shared__ float st[NPB * KC];        // 12.8 KB
  const int t = threadIdx.x, b = blockIdx.x;
  const int g = b >> 3, sub = b & 7;
  const int n0 = g * NPG + sub * NPB;
  // zero adj_raw/scal/done + init bin cursors (first 66 blocks)
  {
    const unsigned gid = (unsigned)b * 256u + (unsigned)t;
    if (gid < 16400u) azero[gid] = 0u;
    else if (gid < 16656u) gcur[gid - 16400u] = (gid - 16400u) * CAP;
  }
  // ---- phase 1: softmax^2 for nodes n0..n0+199 (threads 0..199) ----
  if (t < NPB) {
    float acc[KC];
#pragma unroll
    for (int k = 0; k < KC; ++k) acc[k] = bb[k];
    const float4* xr = (const float4*)(x + (size_t)(n0 + t) * FD);
#pragma unroll 4
    for (int c = 0; c < FD / 4; ++c) {
      float4 v = xr[c];
      const float* wr = W + c * 4 * KC;   // wave-uniform -> scalar loads
#pragma unroll
      for (int k = 0; k < KC; ++k)
        acc[k] += v.x * wr[k] + v.y * wr[KC + k] + v.z * wr[2 * KC + k] + v.w * wr[3 * KC + k];
    }
#pragma unroll
    for (int r = 0; r < 2; ++r) {
      float m = acc[0];
#pragma unroll
      for (int k = 1; k < KC; ++k) m = fmaxf(m, acc[k]);
      float sum = 0.f;
#pragma unroll
      for (int k = 0; k < KC; ++k) { acc[k] = expf(acc[k] - m); sum += acc[k]; }
      float inv = 1.f / sum;
#pragma unroll
      for (int k = 0; k < KC; ++k) acc[k] *= inv;
    }
#pragma unroll
    for (int k = 0; k < KC; ++k) st[t * KC + k] = acc[k];
    float4* so = (float4*)(s + (size_t)(n0 + t) * KC);
    so[0] = make_float4(acc[0], acc[1], acc[2], acc[3]);
    so[1] = make_float4(acc[4], acc[5], acc[6], acc[7]);
    so[2] = make_float4(acc[8], acc[9], acc[10], acc[11]);
    so[3] = make_float4(acc[12], acc[13], acc[14], acc[15]);
  }
  __syncthreads();
  // ---- phase 2: out_x = S^T X and CC = S^T S partials over the block's 200 rows ----
  const int j = t & 127, h2 = t >> 7;
  const int kc = t >> 4, lc = t & 15;
  float accX[8] = {0.f, 0.f, 0.f, 0.f, 0.f, 0.f, 0.f, 0.f};
  float accC = 0.f;
  for (int i = 0; i < NPB; ++i) {
    const float xv = x[(size_t)(n0 + i) * FD + j];   // L2-hot (phase-1 tile)
    const float* si = st + i * KC;
#pragma unroll
    for (int kk = 0; kk < 8; ++kk) accX[kk] = fmaf(si[h2 * 8 + kk], xv, accX[kk]);
    accC = fmaf(si[kc], si[lc], accC);
  }
#pragma unroll
  for (int kk = 0; kk < 8; ++kk)
    outx_part[(size_t)b * 2048 + (h2 * 8 + kk) * 128 + j] = accX[kk];
  cc_part[b * 256 + t] = accC;
}

// ------ scatter v3: reg snapshot -> atomic bin reservation -> LDS stage -> burst ------
// Within-bin edge order is irrelevant (msc3 accumulation is commutative), so exact
// prefix offsets are unnecessary: each block reserves a contiguous run in its bin
// via one atomicAdd(gcur[bin], count) per bin. blkhist/scan kernels deleted.
__global__ __launch_bounds__(256, 4) void k_scatter2(const float* __restrict__ ew,
    const int* __restrict__ esrc, const int* __restrict__ edst,
    unsigned* __restrict__ gcur,
    unsigned short* __restrict__ skey, unsigned* __restrict__ pay) {
  __shared__ unsigned cur[BINS];        // counts -> cursors
  __shared__ unsigned gadj[BINS];       // gstart[bin] - boff[bin]
  __shared__ unsigned wsum[4];
  __shared__ unsigned pays[EH];         // 20.5 KB
  __shared__ unsigned short keys[EH];   // 10.25 KB
  __shared__ unsigned char bmap[EH];    // 5.1 KB
  const int t = threadIdx.x, b = blockIdx.x;
  cur[t] = 0u;
  __syncthreads();
  // pass 1: snapshot edges into registers + block histogram
  unsigned rpay[EPT], rmeta[EPT];       // rmeta = bin<<16 | row-in-bin
  const int e0 = b * EH;
#pragma unroll
  for (int i = 0; i < EPT; ++i) {
    const int e = e0 + t + i * 256;
    int s0 = esrc[e], d0 = edst[e];
    float w = ew[e];
    unsigned bin = (unsigned)s0 / (unsigned)RPB;
    unsigned g = bin >> 2;
    rmeta[i] = (bin << 16) | ((unsigned)s0 - bin * RPB);
    rpay[i] = (((unsigned)d0 - g * NPG) << 16) | f2bf(w);
    atomicAdd(&cur[bin], 1u);           // ds_add, no-return
  }
  __syncthreads();
  // exclusive scan of cur[256] -> block-local offsets; reserve global runs
  {
    unsigned v = cur[t];
    unsigned inc = v;
#pragma unroll
    for (int o = 1; o < 64; o <<= 1) {
      unsigned nb = __shfl_up(inc, o, 64);
      if ((t & 63) >= o) inc += nb;
    }
    if ((t & 63) == 63) wsum[t >> 6] = inc;
    __syncthreads();
    if (t == 0) {
      unsigned run = 0;
#pragma unroll
      for (int i = 0; i < 4; ++i) { unsigned c = wsum[i]; wsum[i] = run; run += c; }
    }
    __syncthreads();
    const unsigned boff = inc - v + wsum[t >> 6];
    const unsigned gstart = atomicAdd(&gcur[t], v);  // reserve [gstart, gstart+v)
    cur[t] = boff;                      // running cursor starts at boff
    gadj[t] = gstart - boff;            // gaddr = gadj[bin] + pos
  }
  __syncthreads();
  // pass 2: rank + scatter into LDS staging (bin-sorted order)
#pragma unroll
  for (int i = 0; i < EPT; ++i) {
    const unsigned bin = rmeta[i] >> 16;
    const unsigned pos = atomicAdd(&cur[bin], 1u);   // ds_add_rtn
    pays[pos] = rpay[i];
    keys[pos] = (unsigned short)(rmeta[i] & 0xFFFFu);
    bmap[pos] = (unsigned char)bin;
  }
  __syncthreads();
  // pass 3: burst flush; consecutive p -> consecutive gaddr within each bin run
  for (int p = t; p < EH; p += 256) {
    const unsigned bin = bmap[p];
    const unsigned ga = gadj[bin] + p;
    pay[ga] = pays[p];
    skey[ga] = keys[p];
  }
}

// ---- k_msc3: s slab in LDS; M bin accumulator in LDS as FIXED-POINT u32 ----
// ds_add_u32 fire-and-forget (FP LDS atomicAdd = CAS loop, R5 lesson). Bin range
// is now [bin*CAP, gcur[bin]) -- no scan needed at all.
__global__ __launch_bounds__(1024, 1) void k_msc3(const float* __restrict__ s,
    const unsigned short* __restrict__ skey, const unsigned* __restrict__ pay,
    const unsigned* __restrict__ gcur, float* __restrict__ adj_raw,
    float* __restrict__ den) {
  __shared__ float SL[NPG * 17];       // 108.8 KB: whole-graph s, stride-17 pad
  __shared__ unsigned Ml[RPB * 17];    // 27.2 KB: bin's M accumulator (x 2^24)
  __shared__ float P[1024];            // 4 KB: adj partial reduce
  __shared__ float scr[16];
  const int t = threadIdx.x;
  // swizzle: all 4 bins of a graph (and 8 graphs) share an XCD
  const int bin = (blockIdx.x & 7) * 32 + (blockIdx.x >> 3);
  const int g = bin >> 2;
  const int q = bin & 3;
  // stage s slab, converting [1600][16] -> padded [1600][17]
  const float4* sg4 = (const float4*)(s + (size_t)g * NPG * KC);
  for (int u4 = t; u4 < NPG * KC / 4; u4 += 1024) {
    float4 v = sg4[u4];
    const int u = u4 * 4;
    float* d = &SL[(u >> 4) * 17 + (u & 15)];
    d[0] = v.x; d[1] = v.y; d[2] = v.z; d[3] = v.w;
  }
  for (int i = t; i < RPB * 17; i += 1024) Ml[i] = 0u;
  __syncthreads();
  const unsigned gb = (unsigned)bin * CAP, ge = gcur[bin];
  const int l = t & 15;
  const int gid = t >> 4;              // 0..63 edge-group id
  const float FXS = 16777216.f;        // 2^24 fixed-point scale
  float dacc = 0.f;
  unsigned e = gb + gid;
  for (; e + 448 < ge; e += 512) {     // 8 independent chains per lane
    unsigned pk0 = pay[e],       pk1 = pay[e + 64];
    unsigned pk2 = pay[e + 128], pk3 = pay[e + 192];
    unsigned pk4 = pay[e + 256], pk5 = pay[e + 320];
    unsigned pk6 = pay[e + 384], pk7 = pay[e + 448];
    unsigned sk0 = skey[e],       sk1 = skey[e + 64];
    unsigned sk2 = skey[e + 128], sk3 = skey[e + 192];
    unsigned sk4 = skey[e + 256], sk5 = skey[e + 320];
    unsigned sk6 = skey[e + 384], sk7 = skey[e + 448];
    float sv0 = SL[(pk0 >> 16) * 17 + l];
    float sv1 = SL[(pk1 >> 16) * 17 + l];
    float sv2 = SL[(pk2 >> 16) * 17 + l];
    float sv3 = SL[(pk3 >> 16) * 17 + l];
    float sv4 = SL[(pk4 >> 16) * 17 + l];
    float sv5 = SL[(pk5 >> 16) * 17 + l];
    float sv6 = SL[(pk6 >> 16) * 17 + l];
    float sv7 = SL[(pk7 >> 16) * 17 + l];
    float t0 = bf2f(pk0 & 0xFFFFu) * sv0;
    float t1 = bf2f(pk1 & 0xFFFFu) * sv1;
    float t2 = bf2f(pk2 & 0xFFFFu) * sv2;
    float t3 = bf2f(pk3 & 0xFFFFu) * sv3;
    float t4 = bf2f(pk4 & 0xFFFFu) * sv4;
    float t5 = bf2f(pk5 & 0xFFFFu) * sv5;
    float t6 = bf2f(pk6 & 0xFFFFu) * sv6;
    float t7 = bf2f(pk7 & 0xFFFFu) * sv7;
    dacc = fmaf(t0, sv0, dacc);
    dacc = fmaf(t1, sv1, dacc);
    dacc = fmaf(t2, sv2, dacc);
    dacc = fmaf(t3, sv3, dacc);
    dacc = fmaf(t4, sv4, dacc);
    dacc = fmaf(t5, sv5, dacc);
    dacc = fmaf(t6, sv6, dacc);
    dacc = fmaf(t7, sv7, dacc);
    atomicAdd(&Ml[sk0 * 17 + l], __float2uint_rn(t0 * FXS));  // ds_add_u32
    atomicAdd(&Ml[sk1 * 17 + l], __float2uint_rn(t1 * FXS));
    atomicAdd(&Ml[sk2 * 17 + l], __float2uint_rn(t2 * FXS));
    atomicAdd(&Ml[sk3 * 17 + l], __float2uint_rn(t3 * FXS));
    atomicAdd(&Ml[sk4 * 17 + l], __float2uint_rn(t4 * FXS));
    atomicAdd(&Ml[sk5 * 17 + l], __float2uint_rn(t5 * FXS));
    atomicAdd(&Ml[sk6 * 17 + l], __float2uint_rn(t6 * FXS));
    atomicAdd(&Ml[sk7 * 17 + l], __float2uint_rn(t7 * FXS));
  }
  for (; e < ge; e += 64) {
    unsigned pk0 = pay[e];
    unsigned sk0 = skey[e];
    float sv0 = SL[(pk0 >> 16) * 17 + l];
    float t0 = bf2f(pk0 & 0xFFFFu) * sv0;
    dacc = fmaf(t0, sv0, dacc);
    atomicAdd(&Ml[sk0 * 17 + l], __float2uint_rn(t0 * FXS));
  }
  __syncthreads();
  // adj contraction: cell (ck,cl) over the bin's 400 rows; 4 threads per cell
  const int ck = (t >> 4) & 15, cl = t & 15, sub = t >> 8;
  float pacc = 0.f;
  const float* SLq = SL + q * RPB * 17;
#pragma unroll 4
  for (int ii = 0; ii < RPB / 4; ++ii) {
    const int r = sub + 4 * ii;
    pacc = fmaf(SLq[r * 17 + ck], (float)Ml[r * 17 + cl], pacc);
  }
  P[t] = pacc;
#pragma unroll
  for (int o = 32; o > 0; o >>= 1) dacc += __shfl_down(dacc, o, 64);
  if ((t & 63) == 0) scr[t >> 6] = dacc;
  __syncthreads();
  if (t < 256) glob_addf(adj_raw + g * 256 + t,
                         (P[t] + P[t + 256] + P[t + 512] + P[t + 768])
                             * 5.9604644775390625e-8f);   // x 2^-24
  if (t == 0) {
    float sum = 0.f;
#pragma unroll
    for (int i = 0; i < 16; ++i) sum += scr[i];
    glob_addf(den, sum);
  }
}

// ---- k_post: normalize adj, trace, ortho (CC partial sum), SELU (outx partials) ----
__device__ __forceinline__ float bred(float v, float* scr) {
#pragma unroll
  for (int o = 32; o > 0; o >>= 1) v += __shfl_down(v, o, 64);
  __syncthreads();
  if ((threadIdx.x & 63) == 0) scr[threadIdx.x >> 6] = v;
  __syncthreads();
  return scr[0] + scr[1] + scr[2] + scr[3];
}

__global__ __launch_bounds__(256) void k_post(const float* __restrict__ adj_raw,
    const float* __restrict__ cc_part, const float* __restrict__ outx_part,
    float* __restrict__ out, float* __restrict__ scal, unsigned* __restrict__ done) {
  const int b = blockIdx.x, t = threadIdx.x;
  const int k = t >> 4, l = t & 15;
  __shared__ float m[16 * 17];
  __shared__ float dk[16];
  __shared__ float scr[4];
  const float raw = adj_raw[b * 256 + t];
  const float masked = (k == l) ? 0.f : raw;
  m[k * 17 + l] = masked;
  __syncthreads();
  if (t < 16) {
    float rs = 0.f;
#pragma unroll
    for (int ll = 0; ll < 16; ++ll) rs += m[t * 17 + ll];
    dk[t] = sqrtf(rs) + 1e-12f;
  }
  __syncthreads();
  out[131072 + b * 256 + t] = masked / (dk[k] * dk[l]);
  float tr = bred((k == l) ? raw : 0.f, scr);
  if (t == 0) glob_addf(scal + 1, tr);
  float c = 0.f;
#pragma unroll
  for (int u = 0; u < 8; ++u) c += cc_part[(b * 8 + u) * 256 + t];
  float n2 = bred(c * c, scr);
  float diff = c / sqrtf(n2) - ((k == l) ? 0.25f : 0.f);
  float d2 = bred(diff * diff, scr);
  if (t == 0) glob_addf(scal + 2, sqrtf(d2));
  for (int idx = b * 256 + t; idx < 131072; idx += 16384) {
    const int gg = idx >> 11, v = idx & 2047;
    float xv = 0.f;
#pragma unroll
    for (int u = 0; u < 8; ++u) xv += outx_part[(size_t)(gg * 8 + u) * 2048 + v];
    out[idx] = xv > 0.f ? 1.0507009873554805f * xv
                        : 1.0507009873554805f * 1.6732632423543772f * expm1f(xv);
  }
  __syncthreads();
  if (t == 0) {
    __threadfence();
    unsigned v = __hip_atomic_fetch_add(done, 1u, __ATOMIC_ACQ_REL,
                                        __HIP_MEMORY_SCOPE_AGENT);
    if (v == 63u) {   // last block: all contributions visible
      float den   = __hip_atomic_load(scal + 0, __ATOMIC_RELAXED, __HIP_MEMORY_SCOPE_AGENT);
      float num   = __hip_atomic_load(scal + 1, __ATOMIC_RELAXED, __HIP_MEMORY_SCOPE_AGENT);
      float ortho = __hip_atomic_load(scal + 2, __ATOMIC_RELAXED, __HIP_MEMORY_SCOPE_AGENT);
      out[147456] = -num / den;
      out[147457] = ortho * (1.f / 64.f);
    }
  }
}

// -------------------- launch --------------------
extern "C" void kernel_launch(void* const* d_in, const int* in_sizes, int n_in,
                              void* d_out, int out_size, void* d_ws, size_t ws_size,
                              hipStream_t stream) {
  const float* x  = (const float*)d_in[0];
  const float* W  = (const float*)d_in[1];
  const float* bb = (const float*)d_in[2];
  const float* ew = (const float*)d_in[3];
  const int* esrc = (const int*)d_in[4];
  const int* edst = (const int*)d_in[5];
  float* out = (float*)d_out;
  float* ws = (float*)d_ws;

  float* s_buf    = ws;                                   // 1,638,400 f
  float* adj_raw  = s_buf + (size_t)NN * KC;              // 16,384 f  <- zeroed by k_s2
  float* scal     = adj_raw + 16384;                      // 8 f: [0]=den [1]=num [2]=ortho
  unsigned* done  = (unsigned*)(scal + 8);                // 8 u       <- end of zero region
  float* cc_part  = (float*)(done + 8);                   // 512*256 f  (per-block partials)
  float* outx_part= cc_part + (size_t)SB * 256;           // 512*2048 f (per-block partials)
  unsigned* gcur  = (unsigned*)(outx_part + (size_t)SB * 2048);  // 256 u (bin cursors)
  unsigned short* skey = (unsigned short*)(gcur + BINS);  // 256*13824 u16
  unsigned* pay = (unsigned*)(skey + (size_t)BINS * CAP); // 256*13824 u32
  // total ~= 32.6 MB (< 33.4 MB proven available)

  k_s2<<<SB, 256, 0, stream>>>(x, W, bb, s_buf, cc_part, outx_part,
                               (unsigned*)adj_raw, gcur);
  k_scatter2<<<HB, 256, 0, stream>>>(ew, esrc, edst, gcur, skey, pay);
  k_msc3<<<BINS, 1024, 0, stream>>>(s_buf, skey, pay, gcur, adj_raw, scal);
  k_post<<<64, 256, 0, stream>>>(adj_raw, cc_part, outx_part, out, scal, done);
}